// Round 1
// baseline (479.475 us; speedup 1.0000x reference)
//
#include <hip/hip_runtime.h>

// ---------------------------------------------------------------------------
// QuantumLayer: B=16384 states of 10 qubits (DIM=1024 complex amps).
// One wave (64 lanes) per state; each lane holds 16 complex amps in VGPRs.
// Amp index k (10 bits): lane = k>>4 (qubit bits 9..4 = qubits 0..5),
//                        reg  = k&15 (qubit bits 3..0 = qubits 6..9).
// CNOTs are never applied to data: we track the GF(2) linear map
// storage = S * logical at COMPILE TIME. A 1q gate on logical bit b pairs
// storage indices k and k^v with v = S e_b (column), and the "side" bit of
// k is parity(R & k) with R = row b of S^{-1}.
// The initial RX layer + layer-0 Rot layer act on |0..0> (product state) and
// are replaced by direct tensor-product construction of the state.
// ---------------------------------------------------------------------------

namespace {

constexpr int NQ = 10;
constexpr int NGATES = 50;   // Rot gates of layers 1..5 (layer 0 fused into init)

struct Sched {
  unsigned v[NGATES];     // storage pair direction
  unsigned R[NGATES];     // parity row (side bit)
  unsigned Rfin[NQ];      // final rows of S^{-1} (for Z-expectation signs)
  bool ok;
};

constexpr int par(unsigned x) { int p = 0; while (x) { p ^= 1; x &= x - 1; } return p; }

constexpr Sched make_sched() {
  Sched s{};
  unsigned cols[NQ] = {};  // columns of S   (cols[b] = S e_b)
  unsigned rows[NQ] = {};  // rows of S^{-1}
  for (int b = 0; b < NQ; ++b) { cols[b] = 1u << b; rows[b] = 1u << b; }
  int g = 0;
  for (int l = 0; l < 6; ++l) {
    if (l > 0) {
      for (int w = 0; w < NQ; ++w) {     // Rot layer l acts on logical qubit w (bit 9-w)
        int b = 9 - w;
        s.v[g] = cols[b];
        s.R[g] = rows[b];
        ++g;
      }
    }
    int r = l % 9 + 1;                   // CNOT ring of layer l
    for (int w = 0; w < NQ; ++w) {
      int c = w, t = (w + r) % NQ;
      int cb = 9 - c, tb = 9 - t;
      cols[cb] ^= cols[tb];              // S' = S P
      rows[tb] ^= rows[cb];              // S'^{-1} = P S^{-1}
    }
  }
  for (int b = 0; b < NQ; ++b) s.Rfin[b] = rows[b];
  // verify S^{-1} S == I
  bool ok = true;
  for (int a = 0; a < NQ; ++a)
    for (int b = 0; b < NQ; ++b)
      if (par(rows[a] & cols[b]) != (a == b ? 1 : 0)) ok = false;
  s.ok = ok;
  return s;
}

constexpr Sched SCH = make_sched();
static_assert(SCH.ok, "GF(2) schedule inconsistent");

} // namespace

// Precomputed Rot 2x2 matrices for all 60 (layer,wire) gates: 8 floats each:
// [u00r,u00i,u01r,u01i,u10r,u10i,u11r,u11i]
__device__ float g_rots[60 * 8];

__global__ void setup_rots_kernel(const float* __restrict__ wts) {
  int idx = threadIdx.x;   // 0..63, use 0..59  (idx = l*10 + w)
  if (idx < 60) {
    float phi = wts[idx * 3 + 0], th = wts[idx * 3 + 1], om = wts[idx * 3 + 2];
    float c, sn;
    sincosf(0.5f * th, &sn, &c);
    float ca, sa, cb, sb;
    sincosf(0.5f * (phi + om), &sa, &ca);
    sincosf(0.5f * (phi - om), &sb, &cb);
    float* o = g_rots + idx * 8;
    o[0] =  ca * c;   o[1] = -sa * c;    // u00 = e^{-i(phi+om)/2} cos(th/2)
    o[2] = -cb * sn;  o[3] = -sb * sn;   // u01 = -e^{+i(phi-om)/2} sin(th/2)
    o[4] =  cb * sn;  o[5] = -sb * sn;   // u10 = e^{-i(phi-om)/2} sin(th/2)
    o[6] =  ca * c;   o[7] =  sa * c;    // u11 = e^{+i(phi+om)/2} cos(th/2)
  }
}

__launch_bounds__(256)
__global__ void qlayer_kernel(const float* __restrict__ x,
                              const float* __restrict__ W,
                              const float* __restrict__ bias,
                              float* __restrict__ out) {
  const int lane = threadIdx.x & 63;
  const int s = blockIdx.x * 4 + (threadIdx.x >> 6);

  // ---- angles = x @ W^T + b ; RX cos/sin ----------------------------------
  const float xl = x[s * 64 + lane];
  float cw[NQ], sw[NQ];
#pragma unroll
  for (int w = 0; w < NQ; ++w) {
    float p = xl * W[w * 64 + lane];
#pragma unroll
    for (int m = 32; m; m >>= 1) p += __shfl_xor(p, m, 64);
    const float half = 0.5f * (p + bias[w]);
    float ss, cc;
    __sincosf(half, &ss, &cc);
    sw[w] = ss; cw[w] = cc;
  }

  // ---- fused per-qubit vector g_w = Rot0_w * RX_w * |0> -------------------
  float g0r[NQ], g0i[NQ], g1r[NQ], g1i[NQ];
#pragma unroll
  for (int w = 0; w < NQ; ++w) {
    const float4 uA = *(const float4*)(g_rots + w * 8);      // u00, u01
    const float4 uB = *(const float4*)(g_rots + w * 8 + 4);  // u10, u11
    const float c = cw[w], sn = sw[w];
    // g = Rot * (c, -i s)^T
    g0r[w] = uA.x * c + uA.w * sn;
    g0i[w] = uA.y * c - uA.z * sn;
    g1r[w] = uB.x * c + uB.w * sn;
    g1i[w] = uB.y * c - uB.z * sn;
  }

  // ---- product state: amp[k] = prod_w g_w[bit_{9-w}(k)] -------------------
  float Fr, Fi;   // lane-common factor (qubits 0..5 <-> lane bits 5..0)
  {
    const int b0 = (lane >> 5) & 1;
    Fr = b0 ? g1r[0] : g0r[0];
    Fi = b0 ? g1i[0] : g0i[0];
#pragma unroll
    for (int w = 1; w < 6; ++w) {
      const int bt = (lane >> (5 - w)) & 1;
      const float gr = bt ? g1r[w] : g0r[w];
      const float gi = bt ? g1i[w] : g0i[w];
      const float nr = Fr * gr - Fi * gi;
      const float ni = Fr * gi + Fi * gr;
      Fr = nr; Fi = ni;
    }
  }

  float ar[16], ai[16];
  {
    float thr[4], thi[4], tlr[4], tli[4];  // qubits (6,7) and (8,9) pair products
#pragma unroll
    for (int a2 = 0; a2 < 4; ++a2) {
      const int bh = (a2 >> 1) & 1, bl = a2 & 1;
      {
        const float xr = bh ? g1r[6] : g0r[6], xi = bh ? g1i[6] : g0i[6];
        const float yr = bl ? g1r[7] : g0r[7], yi = bl ? g1i[7] : g0i[7];
        thr[a2] = xr * yr - xi * yi; thi[a2] = xr * yi + xi * yr;
      }
      {
        const float xr = bh ? g1r[8] : g0r[8], xi = bh ? g1i[8] : g0i[8];
        const float yr = bl ? g1r[9] : g0r[9], yi = bl ? g1i[9] : g0i[9];
        tlr[a2] = xr * yr - xi * yi; tli[a2] = xr * yi + xi * yr;
      }
    }
#pragma unroll
    for (int i = 0; i < 16; ++i) {
      const float pr = thr[i >> 2] * tlr[i & 3] - thi[i >> 2] * tli[i & 3];
      const float pi = thr[i >> 2] * tli[i & 3] + thi[i >> 2] * tlr[i & 3];
      ar[i] = Fr * pr - Fi * pi;
      ai[i] = Fr * pi + Fi * pr;
    }
  }

  // ---- 50 Rot gates along compile-time GF(2) directions -------------------
#pragma unroll
  for (int g = 0; g < NGATES; ++g) {
    const unsigned v = SCH.v[g], R = SCH.R[g];
    const unsigned vl = v & 15u, vh = v >> 4;
    const unsigned Rl = R & 15u, Rh = R >> 4;
    const float4 uA = *(const float4*)(g_rots + (NQ + g) * 8);
    const float4 uB = *(const float4*)(g_rots + (NQ + g) * 8 + 4);
    // side bit of amp (lane,i) = ph ^ parity(i & Rl), ph = parity(lane & Rh)
    const bool ph = (__popc(lane & (int)Rh) & 1) != 0;
    // class A: parity(i&Rl)==0 -> side==ph ; class B: side==ph^1
    const float dAr = ph ? uB.z : uA.x, dAi = ph ? uB.w : uA.y;  // diag coeff
    const float oAr = ph ? uB.x : uA.z, oAi = ph ? uB.y : uA.w;  // off  coeff
    const float dBr = ph ? uA.x : uB.z, dBi = ph ? uA.y : uB.w;
    const float oBr = ph ? uA.z : uB.x, oBi = ph ? uA.w : uB.y;

    if (vh == 0u) {
      // in-register pairs (i, i^vl)
#pragma unroll
      for (int i = 0; i < 16; ++i) {
        const int j = i ^ (int)vl;
        if (j > i) {
          const bool ci = (__popc(i & (int)Rl) & 1) != 0;
          const bool cj = (__popc(j & (int)Rl) & 1) != 0;
          const float d0r = ci ? dBr : dAr, d0i = ci ? dBi : dAi;
          const float o0r = ci ? oBr : oAr, o0i = ci ? oBi : oAi;
          const float d1r = cj ? dBr : dAr, d1i = cj ? dBi : dAi;
          const float o1r = cj ? oBr : oAr, o1i = cj ? oBi : oAi;
          const float xr = ar[i], xi = ai[i], yr = ar[j], yi = ai[j];
          ar[i] = d0r * xr - d0i * xi + o0r * yr - o0i * yi;
          ai[i] = d0r * xi + d0i * xr + o0r * yi + o0i * yr;
          ar[j] = d1r * yr - d1i * yi + o1r * xr - o1i * xi;
          ai[j] = d1r * yi + d1i * yr + o1r * xi + o1i * xr;
        }
      }
    } else if (vl == 0u) {
      // pure cross-lane: partner (lane^vh, i)
#pragma unroll
      for (int i = 0; i < 16; ++i) {
        const float pr = __shfl_xor(ar[i], (int)vh, 64);
        const float pi = __shfl_xor(ai[i], (int)vh, 64);
        const bool ci = (__popc(i & (int)Rl) & 1) != 0;
        const float ddr = ci ? dBr : dAr, ddi = ci ? dBi : dAi;
        const float oor = ci ? oBr : oAr, ooi = ci ? oBi : oAi;
        const float xr = ar[i], xi = ai[i];
        ar[i] = ddr * xr - ddi * xi + oor * pr - ooi * pi;
        ai[i] = ddr * xi + ddi * xr + oor * pi + ooi * pr;
      }
    } else {
      // mixed: amp (lane,i) pairs with (lane^vh, i^vl); process (i,j) together
      // reading partner values before any write (lockstep wave, no hazard)
#pragma unroll
      for (int i = 0; i < 16; ++i) {
        const int j = i ^ (int)vl;
        if (j > i) {
          const float qjr = __shfl_xor(ar[j], (int)vh, 64);
          const float qji = __shfl_xor(ai[j], (int)vh, 64);
          const float qir = __shfl_xor(ar[i], (int)vh, 64);
          const float qii = __shfl_xor(ai[i], (int)vh, 64);
          const bool ci = (__popc(i & (int)Rl) & 1) != 0;
          const bool cj = (__popc(j & (int)Rl) & 1) != 0;
          const float d0r = ci ? dBr : dAr, d0i = ci ? dBi : dAi;
          const float o0r = ci ? oBr : oAr, o0i = ci ? oBi : oAi;
          const float d1r = cj ? dBr : dAr, d1i = cj ? dBi : dAi;
          const float o1r = cj ? oBr : oAr, o1i = cj ? oBi : oAi;
          const float xr = ar[i], xi = ai[i], yr = ar[j], yi = ai[j];
          ar[i] = d0r * xr - d0i * xi + o0r * qjr - o0i * qji;
          ai[i] = d0r * xi + d0i * xr + o0r * qji + o0i * qjr;
          ar[j] = d1r * yr - d1i * yi + o1r * qir - o1i * qii;
          ai[j] = d1r * yi + d1i * yr + o1r * qii + o1i * qir;
        }
      }
    }
  }

  // ---- Z expectations: out[q] = sum_k |amp|^2 * (1-2*parity(Rfin[9-q]&k)) -
  float pb[16];
#pragma unroll
  for (int i = 0; i < 16; ++i) pb[i] = ar[i] * ar[i] + ai[i] * ai[i];
#pragma unroll
  for (int q = 0; q < NQ; ++q) {
    const unsigned R = SCH.Rfin[9 - q];
    const unsigned Rl = R & 15u, Rh = R >> 4;
    float t = 0.f;
#pragma unroll
    for (int i = 0; i < 16; ++i) {
      const bool ci = (__popc(i & (int)Rl) & 1) != 0;
      t = ci ? t - pb[i] : t + pb[i];
    }
    const bool ph = (__popc(lane & (int)Rh) & 1) != 0;
    t = ph ? -t : t;
#pragma unroll
    for (int m = 32; m; m >>= 1) t += __shfl_xor(t, m, 64);
    if (lane == 0) out[s * NQ + q] = t;
  }
}

extern "C" void kernel_launch(void* const* d_in, const int* in_sizes, int n_in,
                              void* d_out, int out_size, void* d_ws, size_t ws_size,
                              hipStream_t stream) {
  const float* x   = (const float*)d_in[0];   // (B, 64)
  const float* W   = (const float*)d_in[1];   // (10, 64)
  const float* b   = (const float*)d_in[2];   // (10,)
  const float* wts = (const float*)d_in[3];   // (6, 10, 3)
  float* out = (float*)d_out;                 // (B, 10)
  const int B = in_sizes[0] / 64;

  setup_rots_kernel<<<1, 64, 0, stream>>>(wts);
  qlayer_kernel<<<B / 4, 256, 0, stream>>>(x, W, b, out);
}

// Round 3
// 252.442 us; speedup vs baseline: 1.8993x; 1.8993x over previous
//
#include <hip/hip_runtime.h>

// ---------------------------------------------------------------------------
// QuantumLayer: B=16384 states of 10 qubits (DIM=1024 complex amps).
// One wave (64 lanes) per state; each lane holds 16 complex amps in VGPRs.
// Amp index k (10 bits): lane = k>>4 (storage bits 9..4), reg = k&15 (bits 3..0).
// CNOTs are compile-time GF(2) index relabeling (matrix S); each Rot gate acts
// along direction v = S e_b with side bit parity(R & k), R = row of S^{-1}.
// Cross-lane partner fetches use ds_swizzle (xor<32, immediate pattern) or
// ds_bpermute (xor>=32, address hoisted per gate) -- no __shfl header bloat.
// ---------------------------------------------------------------------------

namespace {

constexpr int NQ = 10;
constexpr int NGATES = 50;   // Rot gates of layers 1..5 (layer 0 fused into init)

struct Sched {
  unsigned v[NGATES];
  unsigned R[NGATES];
  unsigned Rfin[NQ];
  bool ok;
};

constexpr int par(unsigned x) { int p = 0; while (x) { p ^= 1; x &= x - 1; } return p; }

constexpr Sched make_sched() {
  Sched s{};
  unsigned cols[NQ] = {};
  unsigned rows[NQ] = {};
  for (int b = 0; b < NQ; ++b) { cols[b] = 1u << b; rows[b] = 1u << b; }
  int g = 0;
  for (int l = 0; l < 6; ++l) {
    if (l > 0) {
      for (int w = 0; w < NQ; ++w) {
        int b = 9 - w;
        s.v[g] = cols[b];
        s.R[g] = rows[b];
        ++g;
      }
    }
    int r = l % 9 + 1;
    for (int w = 0; w < NQ; ++w) {
      int c = w, t = (w + r) % NQ;
      int cb = 9 - c, tb = 9 - t;
      cols[cb] ^= cols[tb];
      rows[tb] ^= rows[cb];
    }
  }
  for (int b = 0; b < NQ; ++b) s.Rfin[b] = rows[b];
  bool ok = true;
  for (int a = 0; a < NQ; ++a)
    for (int b = 0; b < NQ; ++b)
      if (par(rows[a] & cols[b]) != (a == b ? 1 : 0)) ok = false;
  s.ok = ok;
  return s;
}

constexpr Sched SCH = make_sched();
static_assert(SCH.ok, "GF(2) schedule inconsistent");

} // namespace

__device__ float g_rots[60 * 8];

__global__ void setup_rots_kernel(const float* __restrict__ wts) {
  int idx = threadIdx.x;
  if (idx < 60) {
    float phi = wts[idx * 3 + 0], th = wts[idx * 3 + 1], om = wts[idx * 3 + 2];
    float c, sn;
    sincosf(0.5f * th, &sn, &c);
    float ca, sa, cb, sb;
    sincosf(0.5f * (phi + om), &sa, &ca);
    sincosf(0.5f * (phi - om), &sb, &cb);
    float* o = g_rots + idx * 8;
    o[0] =  ca * c;   o[1] = -sa * c;
    o[2] = -cb * sn;  o[3] = -sb * sn;
    o[4] =  cb * sn;  o[5] = -sb * sn;
    o[6] =  ca * c;   o[7] =  sa * c;
  }
}

// ---- cross-lane primitives (zero per-value VALU overhead) ------------------
__device__ __forceinline__ float bperm(int baddr, float v) {
  return __int_as_float(__builtin_amdgcn_ds_bpermute(baddr, __float_as_int(v)));
}

template<int M>
__device__ __forceinline__ float swz(float v) {
  // BitMode xor swizzle within 32-lane groups: offset = (xor<<10) | and_mask 0x1F
  return __int_as_float(__builtin_amdgcn_ds_swizzle(__float_as_int(v), (M << 10) | 0x1F));
}

typedef unsigned uint2v __attribute__((ext_vector_type(2)));

// full-wave add-reduction: 5 swizzle-xor levels + permlane32_swap half merge
__device__ __forceinline__ float red64(float t) {
  t += swz<1>(t);  t += swz<2>(t);  t += swz<4>(t);
  t += swz<8>(t);  t += swz<16>(t);
  uint2v r = __builtin_amdgcn_permlane32_swap(__float_as_uint(t), __float_as_uint(t),
                                              false, false);
  return __uint_as_float(r.x) + __uint_as_float(r.y);  // lo-half total + hi-half total
}

// ---- one Rot gate along compile-time direction v, side-row R ---------------
template<int G>
__device__ __forceinline__ void apply_gate(float (&ar)[16], float (&ai)[16],
                                           const int lane) {
  constexpr int v  = (int)SCH.v[G];
  constexpr int R  = (int)SCH.R[G];
  constexpr int vl = v & 15, vh = v >> 4;
  constexpr int Rl = R & 15, Rh = R >> 4;

  const float4 uA = *(const float4*)(g_rots + (NQ + G) * 8);      // u00, u01
  const float4 uB = *(const float4*)(g_rots + (NQ + G) * 8 + 4);  // u10, u11

  bool ph = false;
  if constexpr (Rh != 0) ph = (__popc(lane & Rh) & 1) != 0;
  // class A: parity(i&Rl)==0 -> side==ph ; class B: side==!ph
  const float dAr = ph ? uB.z : uA.x, dAi = ph ? uB.w : uA.y;
  const float oAr = ph ? uB.x : uA.z, oAi = ph ? uB.y : uA.w;
  const float dBr = ph ? uA.x : uB.z, dBi = ph ? uA.y : uB.w;
  const float oBr = ph ? uA.z : uB.x, oBi = ph ? uA.w : uB.y;

  if constexpr (vh == 0) {
    // in-register pairs (i, i^vl)
#pragma unroll
    for (int i = 0; i < 16; ++i) {
      const int j = i ^ vl;
      if (j > i) {
        const bool ci = (__popc(i & Rl) & 1) != 0;   // folds after unroll
        const bool cj = (__popc(j & Rl) & 1) != 0;
        const float d0r = ci ? dBr : dAr, d0i = ci ? dBi : dAi;
        const float o0r = ci ? oBr : oAr, o0i = ci ? oBi : oAi;
        const float d1r = cj ? dBr : dAr, d1i = cj ? dBi : dAi;
        const float o1r = cj ? oBr : oAr, o1i = cj ? oBi : oAi;
        const float xr = ar[i], xi = ai[i], yr = ar[j], yi = ai[j];
        ar[i] = d0r * xr - d0i * xi + o0r * yr - o0i * yi;
        ai[i] = d0r * xi + d0i * xr + o0r * yi + o0i * yr;
        ar[j] = d1r * yr - d1i * yi + o1r * xr - o1i * xi;
        ai[j] = d1r * yi + d1i * yr + o1r * xi + o1i * xr;
      }
    }
  } else {
    int baddr = 0;
    if constexpr (vh >= 32) baddr = (lane ^ vh) << 2;  // hoisted: 2 VALU per gate
    auto fetch = [&](float x) -> float {
      if constexpr (vh < 32) return swz<vh>(x);
      else                   return bperm(baddr, x);
    };

    if constexpr (vl == 0) {
      // pure cross-lane: partner (lane^vh, i)
#pragma unroll
      for (int i = 0; i < 16; ++i) {
        const float pr = fetch(ar[i]);
        const float pi = fetch(ai[i]);
        const bool ci = (__popc(i & Rl) & 1) != 0;
        const float ddr = ci ? dBr : dAr, ddi = ci ? dBi : dAi;
        const float oor = ci ? oBr : oAr, ooi = ci ? oBi : oAi;
        const float xr = ar[i], xi = ai[i];
        ar[i] = ddr * xr - ddi * xi + oor * pr - ooi * pi;
        ai[i] = ddr * xi + ddi * xr + oor * pi + ooi * pr;
      }
    } else {
      // mixed: (lane,i) pairs with (lane^vh, i^vl); fetch before write per pair
#pragma unroll
      for (int i = 0; i < 16; ++i) {
        const int j = i ^ vl;
        if (j > i) {
          const float qjr = fetch(ar[j]);
          const float qji = fetch(ai[j]);
          const float qir = fetch(ar[i]);
          const float qii = fetch(ai[i]);
          const bool ci = (__popc(i & Rl) & 1) != 0;
          const bool cj = (__popc(j & Rl) & 1) != 0;
          const float d0r = ci ? dBr : dAr, d0i = ci ? dBi : dAi;
          const float o0r = ci ? oBr : oAr, o0i = ci ? oBi : oAi;
          const float d1r = cj ? dBr : dAr, d1i = cj ? dBi : dAi;
          const float o1r = cj ? oBr : oAr, o1i = cj ? oBi : oAi;
          const float xr = ar[i], xi = ai[i], yr = ar[j], yi = ai[j];
          ar[i] = d0r * xr - d0i * xi + o0r * qjr - o0i * qji;
          ai[i] = d0r * xi + d0i * xr + o0r * qji + o0i * qjr;
          ar[j] = d1r * yr - d1i * yi + o1r * qir - o1i * qii;
          ai[j] = d1r * yi + d1i * yr + o1r * qii + o1i * qir;
        }
      }
    }
  }
}

template<int G>
__device__ __forceinline__ void run_gates(float (&ar)[16], float (&ai)[16],
                                          const int lane) {
  if constexpr (G < NGATES) {
    apply_gate<G>(ar, ai, lane);
    run_gates<G + 1>(ar, ai, lane);
  }
}

__launch_bounds__(256)
__global__ void qlayer_kernel(const float* __restrict__ x,
                              const float* __restrict__ W,
                              const float* __restrict__ bias,
                              float* __restrict__ out) {
  const int lane = threadIdx.x & 63;
  const int s = blockIdx.x * 4 + (threadIdx.x >> 6);

  // ---- angles = x @ W^T + b ; RX cos/sin ----------------------------------
  const float xl = x[s * 64 + lane];
  float cw[NQ], sw[NQ];
#pragma unroll
  for (int w = 0; w < NQ; ++w) {
    const float p = red64(xl * W[w * 64 + lane]);
    const float half = 0.5f * (p + bias[w]);
    float ss, cc;
    __sincosf(half, &ss, &cc);
    sw[w] = ss; cw[w] = cc;
  }

  // ---- fused per-qubit vector g_w = Rot0_w * RX_w * |0> -------------------
  float g0r[NQ], g0i[NQ], g1r[NQ], g1i[NQ];
#pragma unroll
  for (int w = 0; w < NQ; ++w) {
    const float4 uA = *(const float4*)(g_rots + w * 8);
    const float4 uB = *(const float4*)(g_rots + w * 8 + 4);
    const float c = cw[w], sn = sw[w];
    g0r[w] = uA.x * c + uA.w * sn;
    g0i[w] = uA.y * c - uA.z * sn;
    g1r[w] = uB.x * c + uB.w * sn;
    g1i[w] = uB.y * c - uB.z * sn;
  }

  // ---- product state ------------------------------------------------------
  float Fr, Fi;
  {
    const int b0 = (lane >> 5) & 1;
    Fr = b0 ? g1r[0] : g0r[0];
    Fi = b0 ? g1i[0] : g0i[0];
#pragma unroll
    for (int w = 1; w < 6; ++w) {
      const int bt = (lane >> (5 - w)) & 1;
      const float gr = bt ? g1r[w] : g0r[w];
      const float gi = bt ? g1i[w] : g0i[w];
      const float nr = Fr * gr - Fi * gi;
      const float ni = Fr * gi + Fi * gr;
      Fr = nr; Fi = ni;
    }
  }

  float ar[16], ai[16];
  {
    float thr[4], thi[4], tlr[4], tli[4];
#pragma unroll
    for (int a2 = 0; a2 < 4; ++a2) {
      const int bh = (a2 >> 1) & 1, bl = a2 & 1;
      {
        const float xr = bh ? g1r[6] : g0r[6], xi = bh ? g1i[6] : g0i[6];
        const float yr = bl ? g1r[7] : g0r[7], yi = bl ? g1i[7] : g0i[7];
        thr[a2] = xr * yr - xi * yi; thi[a2] = xr * yi + xi * yr;
      }
      {
        const float xr = bh ? g1r[8] : g0r[8], xi = bh ? g1i[8] : g0i[8];
        const float yr = bl ? g1r[9] : g0r[9], yi = bl ? g1i[9] : g0i[9];
        tlr[a2] = xr * yr - xi * yi; tli[a2] = xr * yi + xi * yr;
      }
    }
#pragma unroll
    for (int i = 0; i < 16; ++i) {
      const float pr = thr[i >> 2] * tlr[i & 3] - thi[i >> 2] * tli[i & 3];
      const float pi = thr[i >> 2] * tli[i & 3] + thi[i >> 2] * tlr[i & 3];
      ar[i] = Fr * pr - Fi * pi;
      ai[i] = Fr * pi + Fi * pr;
    }
  }

  // ---- 50 Rot gates -------------------------------------------------------
  run_gates<0>(ar, ai, lane);

  // ---- Z expectations -----------------------------------------------------
  float pb[16];
#pragma unroll
  for (int i = 0; i < 16; ++i) pb[i] = ar[i] * ar[i] + ai[i] * ai[i];
#pragma unroll
  for (int q = 0; q < NQ; ++q) {
    const int R = (int)SCH.Rfin[9 - q];
    const int Rl = R & 15, Rh = R >> 4;
    float t = 0.f;
#pragma unroll
    for (int i = 0; i < 16; ++i) {
      const bool ci = (__popc(i & Rl) & 1) != 0;   // compile-time sign
      t = ci ? t - pb[i] : t + pb[i];
    }
    if (Rh != 0) {
      const bool ph = (__popc(lane & Rh) & 1) != 0;
      t = ph ? -t : t;
    }
    t = red64(t);
    if (lane == 0) out[s * NQ + q] = t;
  }
}

extern "C" void kernel_launch(void* const* d_in, const int* in_sizes, int n_in,
                              void* d_out, int out_size, void* d_ws, size_t ws_size,
                              hipStream_t stream) {
  const float* x   = (const float*)d_in[0];
  const float* W   = (const float*)d_in[1];
  const float* b   = (const float*)d_in[2];
  const float* wts = (const float*)d_in[3];
  float* out = (float*)d_out;
  const int B = in_sizes[0] / 64;

  setup_rots_kernel<<<1, 64, 0, stream>>>(wts);
  qlayer_kernel<<<B / 4, 256, 0, stream>>>(x, W, b, out);
}

// Round 4
// 250.598 us; speedup vs baseline: 1.9133x; 1.0074x over previous
//
#include <hip/hip_runtime.h>

// ---------------------------------------------------------------------------
// QuantumLayer: B=16384 states of 10 qubits (DIM=1024 complex amps).
// One wave (64 lanes) per state; each lane holds 16 complex amps in VGPRs.
// Amp index k (10 bits): lane = k>>4 (storage bits 9..4), reg = k&15 (bits 3..0).
// CNOTs are compile-time GF(2) index relabeling (matrix S); each Rot gate acts
// along direction v = S e_b with side bit parity(R & k), R = row of S^{-1}.
// Cross-lane partner fetches: ds_swizzle (xor<32) / ds_bpermute (xor>=32).
// R4: distance-1 software-pipelined coefficient prefetch (hide L2 vmcnt under
// the previous gate's FMA block) + Walsh-Hadamard readout (64 adds vs 160).
// ---------------------------------------------------------------------------

namespace {

constexpr int NQ = 10;
constexpr int NGATES = 50;   // Rot gates of layers 1..5 (layer 0 fused into init)

struct Sched {
  unsigned v[NGATES];
  unsigned R[NGATES];
  unsigned Rfin[NQ];
  bool ok;
};

constexpr int par(unsigned x) { int p = 0; while (x) { p ^= 1; x &= x - 1; } return p; }

constexpr Sched make_sched() {
  Sched s{};
  unsigned cols[NQ] = {};
  unsigned rows[NQ] = {};
  for (int b = 0; b < NQ; ++b) { cols[b] = 1u << b; rows[b] = 1u << b; }
  int g = 0;
  for (int l = 0; l < 6; ++l) {
    if (l > 0) {
      for (int w = 0; w < NQ; ++w) {
        int b = 9 - w;
        s.v[g] = cols[b];
        s.R[g] = rows[b];
        ++g;
      }
    }
    int r = l % 9 + 1;
    for (int w = 0; w < NQ; ++w) {
      int c = w, t = (w + r) % NQ;
      int cb = 9 - c, tb = 9 - t;
      cols[cb] ^= cols[tb];
      rows[tb] ^= rows[cb];
    }
  }
  for (int b = 0; b < NQ; ++b) s.Rfin[b] = rows[b];
  bool ok = true;
  for (int a = 0; a < NQ; ++a)
    for (int b = 0; b < NQ; ++b)
      if (par(rows[a] & cols[b]) != (a == b ? 1 : 0)) ok = false;
  s.ok = ok;
  return s;
}

constexpr Sched SCH = make_sched();
static_assert(SCH.ok, "GF(2) schedule inconsistent");

} // namespace

__device__ float g_rots[60 * 8];

__global__ void setup_rots_kernel(const float* __restrict__ wts) {
  int idx = threadIdx.x;
  if (idx < 60) {
    float phi = wts[idx * 3 + 0], th = wts[idx * 3 + 1], om = wts[idx * 3 + 2];
    float c, sn;
    sincosf(0.5f * th, &sn, &c);
    float ca, sa, cb, sb;
    sincosf(0.5f * (phi + om), &sa, &ca);
    sincosf(0.5f * (phi - om), &sb, &cb);
    float* o = g_rots + idx * 8;
    o[0] =  ca * c;   o[1] = -sa * c;
    o[2] = -cb * sn;  o[3] = -sb * sn;
    o[4] =  cb * sn;  o[5] = -sb * sn;
    o[6] =  ca * c;   o[7] =  sa * c;
  }
}

// ---- cross-lane primitives (zero per-value VALU overhead) ------------------
__device__ __forceinline__ float bperm(int baddr, float v) {
  return __int_as_float(__builtin_amdgcn_ds_bpermute(baddr, __float_as_int(v)));
}

template<int M>
__device__ __forceinline__ float swz(float v) {
  // BitMode xor swizzle within 32-lane groups: offset = (xor<<10) | and_mask 0x1F
  return __int_as_float(__builtin_amdgcn_ds_swizzle(__float_as_int(v), (M << 10) | 0x1F));
}

typedef unsigned uint2v __attribute__((ext_vector_type(2)));

// full-wave add-reduction: 5 swizzle-xor levels + permlane32_swap half merge
__device__ __forceinline__ float red64(float t) {
  t += swz<1>(t);  t += swz<2>(t);  t += swz<4>(t);
  t += swz<8>(t);  t += swz<16>(t);
  uint2v r = __builtin_amdgcn_permlane32_swap(__float_as_uint(t), __float_as_uint(t),
                                              false, false);
  return __uint_as_float(r.x) + __uint_as_float(r.y);  // lo-half + hi-half totals
}

// ---- one Rot gate along compile-time direction v, side-row R ---------------
template<int G>
__device__ __forceinline__ void apply_gate(const float4 uA, const float4 uB,
                                           float (&ar)[16], float (&ai)[16],
                                           const int lane) {
  constexpr int v  = (int)SCH.v[G];
  constexpr int R  = (int)SCH.R[G];
  constexpr int vl = v & 15, vh = v >> 4;
  constexpr int Rl = R & 15, Rh = R >> 4;

  bool ph = false;
  if constexpr (Rh != 0) ph = (__popc(lane & Rh) & 1) != 0;
  // class A: parity(i&Rl)==0 -> side==ph ; class B: side==!ph
  const float dAr = ph ? uB.z : uA.x, dAi = ph ? uB.w : uA.y;
  const float oAr = ph ? uB.x : uA.z, oAi = ph ? uB.y : uA.w;
  const float dBr = ph ? uA.x : uB.z, dBi = ph ? uA.y : uB.w;
  const float oBr = ph ? uA.z : uB.x, oBi = ph ? uA.w : uB.y;

  if constexpr (vh == 0) {
    // in-register pairs (i, i^vl)
#pragma unroll
    for (int i = 0; i < 16; ++i) {
      const int j = i ^ vl;
      if (j > i) {
        const bool ci = (__popc(i & Rl) & 1) != 0;   // compile-time after unroll
        const bool cj = (__popc(j & Rl) & 1) != 0;
        const float d0r = ci ? dBr : dAr, d0i = ci ? dBi : dAi;
        const float o0r = ci ? oBr : oAr, o0i = ci ? oBi : oAi;
        const float d1r = cj ? dBr : dAr, d1i = cj ? dBi : dAi;
        const float o1r = cj ? oBr : oAr, o1i = cj ? oBi : oAi;
        const float xr = ar[i], xi = ai[i], yr = ar[j], yi = ai[j];
        ar[i] = d0r * xr - d0i * xi + o0r * yr - o0i * yi;
        ai[i] = d0r * xi + d0i * xr + o0r * yi + o0i * yr;
        ar[j] = d1r * yr - d1i * yi + o1r * xr - o1i * xi;
        ai[j] = d1r * yi + d1i * yr + o1r * xi + o1i * xr;
      }
    }
  } else {
    int baddr = 0;
    if constexpr (vh >= 32) baddr = (lane ^ vh) << 2;  // hoisted: 2 VALU per gate
    auto fetch = [&](float x) -> float {
      if constexpr (vh < 32) return swz<vh>(x);
      else                   return bperm(baddr, x);
    };

    if constexpr (vl == 0) {
      // pure cross-lane: partner (lane^vh, i)
#pragma unroll
      for (int i = 0; i < 16; ++i) {
        const float pr = fetch(ar[i]);
        const float pi = fetch(ai[i]);
        const bool ci = (__popc(i & Rl) & 1) != 0;
        const float ddr = ci ? dBr : dAr, ddi = ci ? dBi : dAi;
        const float oor = ci ? oBr : oAr, ooi = ci ? oBi : oAi;
        const float xr = ar[i], xi = ai[i];
        ar[i] = ddr * xr - ddi * xi + oor * pr - ooi * pi;
        ai[i] = ddr * xi + ddi * xr + oor * pi + ooi * pr;
      }
    } else {
      // mixed: (lane,i) pairs with (lane^vh, i^vl); fetch before write per pair
#pragma unroll
      for (int i = 0; i < 16; ++i) {
        const int j = i ^ vl;
        if (j > i) {
          const float qjr = fetch(ar[j]);
          const float qji = fetch(ai[j]);
          const float qir = fetch(ar[i]);
          const float qii = fetch(ai[i]);
          const bool ci = (__popc(i & Rl) & 1) != 0;
          const bool cj = (__popc(j & Rl) & 1) != 0;
          const float d0r = ci ? dBr : dAr, d0i = ci ? dBi : dAi;
          const float o0r = ci ? oBr : oAr, o0i = ci ? oBi : oAi;
          const float d1r = cj ? dBr : dAr, d1i = cj ? dBi : dAi;
          const float o1r = cj ? oBr : oAr, o1i = cj ? oBi : oAi;
          const float xr = ar[i], xi = ai[i], yr = ar[j], yi = ai[j];
          ar[i] = d0r * xr - d0i * xi + o0r * qjr - o0i * qji;
          ai[i] = d0r * xi + d0i * xr + o0r * qji + o0i * qjr;
          ar[j] = d1r * yr - d1i * yi + o1r * qir - o1i * qii;
          ai[j] = d1r * yi + d1i * yr + o1r * qii + o1i * qir;
        }
      }
    }
  }
}

// Distance-1 software pipeline: gate G+1's coefficient loads issue BEFORE
// gate G's FMA block, hiding the ~200cy L2 latency under compute.
template<int G>
__device__ __forceinline__ void run_gates(const float4 uA, const float4 uB,
                                          float (&ar)[16], float (&ai)[16],
                                          const int lane) {
  float4 nA, nB;
  if constexpr (G + 1 < NGATES) {
    nA = *(const float4*)(g_rots + (NQ + G + 1) * 8);
    nB = *(const float4*)(g_rots + (NQ + G + 1) * 8 + 4);
  }
  apply_gate<G>(uA, uB, ar, ai, lane);
  if constexpr (G + 1 < NGATES) run_gates<G + 1>(nA, nB, ar, ai, lane);
}

__launch_bounds__(256)
__global__ void qlayer_kernel(const float* __restrict__ x,
                              const float* __restrict__ W,
                              const float* __restrict__ bias,
                              float* __restrict__ out) {
  const int lane = threadIdx.x & 63;
  const int s = blockIdx.x * 4 + (threadIdx.x >> 6);

  // ---- angles = x @ W^T + b ; RX cos/sin ----------------------------------
  // batch all independent loads up front so they overlap
  const float xl = x[s * 64 + lane];
  float wl[NQ];
#pragma unroll
  for (int w = 0; w < NQ; ++w) wl[w] = W[w * 64 + lane];

  float cw[NQ], sw[NQ];
#pragma unroll
  for (int w = 0; w < NQ; ++w) {
    const float p = red64(xl * wl[w]);
    const float half = 0.5f * (p + bias[w]);
    float ss, cc;
    __sincosf(half, &ss, &cc);
    sw[w] = ss; cw[w] = cc;
  }

  // ---- fused per-qubit vector g_w = Rot0_w * RX_w * |0> -------------------
  float g0r[NQ], g0i[NQ], g1r[NQ], g1i[NQ];
#pragma unroll
  for (int w = 0; w < NQ; ++w) {
    const float4 uA = *(const float4*)(g_rots + w * 8);
    const float4 uB = *(const float4*)(g_rots + w * 8 + 4);
    const float c = cw[w], sn = sw[w];
    g0r[w] = uA.x * c + uA.w * sn;
    g0i[w] = uA.y * c - uA.z * sn;
    g1r[w] = uB.x * c + uB.w * sn;
    g1i[w] = uB.y * c - uB.z * sn;
  }

  // ---- product state ------------------------------------------------------
  float Fr, Fi;
  {
    const int b0 = (lane >> 5) & 1;
    Fr = b0 ? g1r[0] : g0r[0];
    Fi = b0 ? g1i[0] : g0i[0];
#pragma unroll
    for (int w = 1; w < 6; ++w) {
      const int bt = (lane >> (5 - w)) & 1;
      const float gr = bt ? g1r[w] : g0r[w];
      const float gi = bt ? g1i[w] : g0i[w];
      const float nr = Fr * gr - Fi * gi;
      const float ni = Fr * gi + Fi * gr;
      Fr = nr; Fi = ni;
    }
  }

  float ar[16], ai[16];
  {
    float thr[4], thi[4], tlr[4], tli[4];
#pragma unroll
    for (int a2 = 0; a2 < 4; ++a2) {
      const int bh = (a2 >> 1) & 1, bl = a2 & 1;
      {
        const float xr = bh ? g1r[6] : g0r[6], xi = bh ? g1i[6] : g0i[6];
        const float yr = bl ? g1r[7] : g0r[7], yi = bl ? g1i[7] : g0i[7];
        thr[a2] = xr * yr - xi * yi; thi[a2] = xr * yi + xi * yr;
      }
      {
        const float xr = bh ? g1r[8] : g0r[8], xi = bh ? g1i[8] : g0i[8];
        const float yr = bl ? g1r[9] : g0r[9], yi = bl ? g1i[9] : g0i[9];
        tlr[a2] = xr * yr - xi * yi; tli[a2] = xr * yi + xi * yr;
      }
    }
#pragma unroll
    for (int i = 0; i < 16; ++i) {
      const float pr = thr[i >> 2] * tlr[i & 3] - thi[i >> 2] * tli[i & 3];
      const float pi = thr[i >> 2] * tli[i & 3] + thi[i >> 2] * tlr[i & 3];
      ar[i] = Fr * pr - Fi * pi;
      ai[i] = Fr * pi + Fi * pr;
    }
  }

  // ---- 50 Rot gates (pipelined coefficient prefetch) ----------------------
  {
    const float4 uA0 = *(const float4*)(g_rots + NQ * 8);
    const float4 uB0 = *(const float4*)(g_rots + NQ * 8 + 4);
    run_gates<0>(uA0, uB0, ar, ai, lane);
  }

  // ---- Z expectations via 4-bit Walsh-Hadamard transform ------------------
  // wht[m] = sum_i pb[i] * (-1)^parity(i&m); out[q] needs m = Rl(q) + lane sign
  float pb[16];
#pragma unroll
  for (int i = 0; i < 16; ++i) pb[i] = ar[i] * ar[i] + ai[i] * ai[i];
#pragma unroll
  for (int lev = 1; lev < 16; lev <<= 1) {
#pragma unroll
    for (int i = 0; i < 16; ++i) {
      if (!(i & lev)) {
        const float A = pb[i], Bv = pb[i | lev];
        pb[i] = A + Bv;
        pb[i | lev] = A - Bv;
      }
    }
  }
#pragma unroll
  for (int q = 0; q < NQ; ++q) {
    const int R = (int)SCH.Rfin[9 - q];
    const int Rl = R & 15, Rh = R >> 4;
    float t = pb[Rl];
    if (Rh != 0) {
      const bool ph = (__popc(lane & Rh) & 1) != 0;
      t = ph ? -t : t;
    }
    t = red64(t);
    if (lane == 0) out[s * NQ + q] = t;
  }
}

extern "C" void kernel_launch(void* const* d_in, const int* in_sizes, int n_in,
                              void* d_out, int out_size, void* d_ws, size_t ws_size,
                              hipStream_t stream) {
  const float* x   = (const float*)d_in[0];
  const float* W   = (const float*)d_in[1];
  const float* b   = (const float*)d_in[2];
  const float* wts = (const float*)d_in[3];
  float* out = (float*)d_out;
  const int B = in_sizes[0] / 64;

  setup_rots_kernel<<<1, 64, 0, stream>>>(wts);
  qlayer_kernel<<<B / 4, 256, 0, stream>>>(x, W, b, out);
}